// Round 6
// baseline (13270.912 us; speedup 1.0000x reference)
//
#include <hip/hip_runtime.h>

#define HIDN 150
#define NG   600     // 4*HIDN gates
#define NGP  640     // padded gate width / G row stride
#define TT   512
#define NBATCH 256
#define KPA  160     // padded K for H buffers / Whh
#define KPE  320     // padded K for embedding

typedef __attribute__((ext_vector_type(8))) short bf16x8;
typedef __attribute__((ext_vector_type(4))) float f32x4;

__device__ __forceinline__ unsigned short f2bf(float v) {
    unsigned int u = __builtin_bit_cast(unsigned int, v);
    u += 0x7fffu + ((u >> 16) & 1u);          // RNE
    return (unsigned short)(u >> 16);
}
__device__ __forceinline__ float bf2f(unsigned short h) {
    unsigned int u = ((unsigned int)h) << 16;
    return __builtin_bit_cast(float, u);
}

#define GLDS(gp, lp) __builtin_amdgcn_global_load_lds( \
    (const __attribute__((address_space(1))) unsigned int*)(gp), \
    (__attribute__((address_space(3))) unsigned int*)(lp), 16, 0, 0)

// ---------------- embedding split ----------------
__global__ __launch_bounds__(256) void embprep_kernel(
    const float* __restrict__ emb,
    unsigned short* __restrict__ eh, unsigned short* __restrict__ el)
{
    int i = blockIdx.x * 256 + threadIdx.x;
    if (i >= 50000 * KPE) return;
    int v = i / KPE, k = i - v * KPE;
    float x = (k < 300) ? emb[(size_t)v * 300 + k] : 0.f;
    unsigned short hi = f2bf(x);
    eh[i] = hi;
    el[i] = f2bf(x - bf2f(hi));
}

// ---------------- generic [600][K] fp32 -> [640][Kp] bf16 hi/lo split ----------------
__global__ __launch_bounds__(256) void split_kernel(
    const float* __restrict__ src, int K, int Kp,
    unsigned short* __restrict__ dh, unsigned short* __restrict__ dl)
{
    int i = blockIdx.x * 256 + threadIdx.x;
    if (i >= NGP * Kp) return;
    int n = i / Kp, k = i - n * Kp;
    float w = (n < NG && k < K) ? src[(size_t)n * K + k] : 0.f;
    unsigned short hi = f2bf(w);
    dh[i] = hi;
    dl[i] = f2bf(w - bf2f(hi));
}

__global__ __launch_bounds__(256) void bias_kernel(
    const float* __restrict__ bih, const float* __restrict__ bhh,
    float* __restrict__ bsum)
{
    int g = blockIdx.x * 256 + threadIdx.x;
    if (g < NGP) bsum[g] = (g < NG) ? (bih[g] + bhh[g]) : 0.f;
}

// ---------------- x_proj GEMM: split-bf16 MFMA ----------------
// M rows = NBc*Tc in 16-batch-interleaved order: rg = bg*(16*Tc) + tl*16 + m16.
// G stored natural column order, row stride 640.
__global__ __launch_bounds__(256, 2) void gemm_kernel(
    const unsigned short* __restrict__ Ah, const unsigned short* __restrict__ Al,
    const int* __restrict__ gather,
    const unsigned short* __restrict__ Eh, const unsigned short* __restrict__ El,
    int Kp,
    const unsigned short* __restrict__ Wh, const unsigned short* __restrict__ Wl,
    const float* __restrict__ bsum, const int* __restrict__ lengths,
    float* __restrict__ G,                                       // [NBc*Tc][640]
    int b_off, int t0, int lTc)
{
    int m0 = blockIdx.x * 128;
    int n0 = blockIdx.y * 128;
    int grpm = (1 << (lTc + 4)) - 1;
    {   // group-level early skip: tile rows all within one 16-batch group
        int bg = m0 >> (lTc + 4);
        int tl0 = (m0 & grpm) >> 4;
        int bm = 0;
        for (int i = 0; i < 16; ++i) bm = max(bm, lengths[b_off + bg * 16 + i]);
        if (t0 + tl0 >= bm) return;
    }

    __shared__ __align__(16) unsigned short Ash[128][32];
    __shared__ __align__(16) unsigned short Asl[128][32];
    __shared__ __align__(16) unsigned short Bsh[128][32];
    __shared__ __align__(16) unsigned short Bsl[128][32];

    int tid = threadIdx.x, lane = tid & 63, wave = tid >> 6;

    const unsigned short* AhB = gather ? Eh : Ah;
    const unsigned short* AlB = gather ? El : Al;
    size_t ra[2], rb[2];
    int mrow[2];
    #pragma unroll
    for (int c2 = 0; c2 < 2; ++c2) {
        int mb = wave * 32 + c2 * 16;
        mrow[c2] = mb;
        int rg = m0 + mb + (lane >> 2);
        int bg = rg >> (lTc + 4);
        int r2 = rg & grpm;
        int tl = r2 >> 4, m16 = r2 & 15;
        int bl = bg * 16 + m16;
        ra[c2] = gather ? (size_t)gather[(b_off + bl) * TT + t0 + tl] * (size_t)Kp
                        : ((size_t)bl * TT + t0 + tl) * (size_t)Kp;
        int nr = n0 + mb + (lane >> 2);
        rb[c2] = (size_t)nr * (size_t)Kp;
    }
    int klane = (lane & 3) * 8;

    f32x4 acc[4][4];
    #pragma unroll
    for (int i = 0; i < 4; ++i)
        #pragma unroll
        for (int j = 0; j < 4; ++j) acc[i][j] = (f32x4){0.f, 0.f, 0.f, 0.f};

    int fr = (lane >> 4) * 8;
    int ml = lane & 15;
    int mbase = (wave & 1) * 64;
    int nbase = (wave >> 1) * 64;

    for (int k0 = 0; k0 < Kp; k0 += 32) {
        #pragma unroll
        for (int c2 = 0; c2 < 2; ++c2) {
            GLDS(AhB + ra[c2] + k0 + klane, &Ash[mrow[c2]][0]);
            GLDS(AlB + ra[c2] + k0 + klane, &Asl[mrow[c2]][0]);
            GLDS(Wh  + rb[c2] + k0 + klane, &Bsh[mrow[c2]][0]);
            GLDS(Wl  + rb[c2] + k0 + klane, &Bsl[mrow[c2]][0]);
        }
        __syncthreads();

        bf16x8 afh[4], afl[4], bfh[4], bfl[4];
        #pragma unroll
        for (int i = 0; i < 4; ++i) {
            afh[i] = *(const bf16x8*)&Ash[mbase + i * 16 + ml][fr];
            afl[i] = *(const bf16x8*)&Asl[mbase + i * 16 + ml][fr];
            bfh[i] = *(const bf16x8*)&Bsh[nbase + i * 16 + ml][fr];
            bfl[i] = *(const bf16x8*)&Bsl[nbase + i * 16 + ml][fr];
        }
        #pragma unroll
        for (int i = 0; i < 4; ++i)
            #pragma unroll
            for (int j = 0; j < 4; ++j)
                acc[i][j] = __builtin_amdgcn_mfma_f32_16x16x32_bf16(afh[i], bfh[j], acc[i][j], 0, 0, 0);
        #pragma unroll
        for (int i = 0; i < 4; ++i)
            #pragma unroll
            for (int j = 0; j < 4; ++j)
                acc[i][j] = __builtin_amdgcn_mfma_f32_16x16x32_bf16(afh[i], bfl[j], acc[i][j], 0, 0, 0);
        #pragma unroll
        for (int i = 0; i < 4; ++i)
            #pragma unroll
            for (int j = 0; j < 4; ++j)
                acc[i][j] = __builtin_amdgcn_mfma_f32_16x16x32_bf16(afl[i], bfh[j], acc[i][j], 0, 0, 0);
        __syncthreads();
    }

    int rq = lane >> 4;
    #pragma unroll
    for (int i = 0; i < 4; ++i) {
        int mg = m0 + mbase + i * 16 + rq * 4;
        #pragma unroll
        for (int j = 0; j < 4; ++j) {
            int ng = n0 + nbase + j * 16 + ml;
            float bz = bsum[ng];
            #pragma unroll
            for (int r = 0; r < 4; ++r)
                G[(size_t)(mg + r) * NGP + ng] = acc[i][j][r] + bz;
        }
    }
}

// ---------------- recurrent scan: MFMA, 16 batches per block ----------------
// 512 threads = 8 waves; wave w owns n-tiles 5w..5w+4 (columns 80w..80w+79).
// Whh split-bf16 fragments resident in ~200 VGPRs; h in LDS (bf16 hi/lo, stride 168);
// G double-buffered in LDS via global_load_lds; gates exchanged via strided LDS.
#define GS(g, u, m) (((g) * 151 + (u)) * 17 + (m))

__global__ __launch_bounds__(512, 2) void scan_kernel(
    const float* __restrict__ G,        // [NBc/16][Tc][16][640]
    const unsigned short* __restrict__ Whs, const unsigned short* __restrict__ Wls, // [640][160]
    const int* __restrict__ lengths,
    unsigned short* __restrict__ Aout, unsigned short* __restrict__ Alout, // [NBc][512][160] or null
    float* __restrict__ hnb,            // [256][150] global batch idx
    float* __restrict__ hst, float* __restrict__ cst,   // [NBc][150] carries
    int b_off, int t0, int Tc)
{
    __shared__ __align__(16) float Gbuf[2][16 * NGP];       // 81.9 KB
    __shared__ float gate_s[4 * 151 * 17];                  // 41.1 KB
    __shared__ __align__(16) unsigned short h_hi[16][168];  // 5.4 KB
    __shared__ __align__(16) unsigned short h_lo[16][168];  // 5.4 KB
    __shared__ int len_s[16];

    int tid = threadIdx.x;
    int lane = tid & 63, w = tid >> 6;
    int ml = lane & 15, quad = lane >> 4;
    int fr = quad * 8;
    int bl16 = blockIdx.x * 16;         // chunk-local batch base
    int bB = b_off + bl16;              // global batch base

    // ---- resident Whh fragments: 5 ntiles x 5 ksteps x (hi,lo) = 200 VGPRs ----
    bf16x8 Bh[5][5], Bl[5][5];
    #pragma unroll
    for (int q = 0; q < 5; ++q) {
        int ncol = w * 80 + q * 16 + ml;
        #pragma unroll
        for (int ks = 0; ks < 5; ++ks) {
            Bh[q][ks] = *(const bf16x8*)&Whs[(size_t)ncol * KPA + ks * 32 + fr];
            Bl[q][ks] = *(const bf16x8*)&Wls[(size_t)ncol * KPA + ks * 32 + fr];
        }
    }

    if (tid < 16) len_s[tid] = lengths[bB + tid];
    for (int i = tid; i < 16 * 168; i += 512) {
        h_hi[0][i] = 0; h_lo[0][i] = 0;
    }

    // ---- per-pair state: thread handles (m,u) pairs pi = tid + 512p ----
    float creg[5], hreg[5];
    #pragma unroll
    for (int p = 0; p < 5; ++p) { creg[p] = 0.f; hreg[p] = 0.f; }
    if (t0 > 0) {
        #pragma unroll
        for (int p = 0; p < 5; ++p) {
            int pi = tid + 512 * p;
            if (pi < 16 * HIDN) {
                int m = pi / HIDN, u = pi - m * HIDN;
                hreg[p] = hst[(bl16 + m) * HIDN + u];
                creg[p] = cst[(bl16 + m) * HIDN + u];
            }
        }
    }
    __syncthreads();
    if (t0 > 0) {
        #pragma unroll
        for (int p = 0; p < 5; ++p) {
            int pi = tid + 512 * p;
            if (pi < 16 * HIDN) {
                int m = pi / HIDN, u = pi - m * HIDN;
                unsigned short hi = f2bf(hreg[p]);
                h_hi[m][u] = hi;
                h_lo[m][u] = f2bf(hreg[p] - bf2f(hi));
            }
        }
    }

    int bm = 0;
    for (int i = 0; i < 16; ++i) bm = max(bm, len_s[i]);
    int tmax = min(bm, t0 + Tc);

    const float* Gblk = G + (size_t)blockIdx.x * Tc * (16 * NGP);
    // stage G slab for step tl into Gbuf[buf]
    #define STAGE(bufi, tl) do { \
        const float* slab_ = Gblk + (size_t)(tl) * (16 * NGP); \
        _Pragma("unroll") \
        for (int i_ = 0; i_ < 5; ++i_) \
            GLDS(slab_ + i_ * 2048 + w * 256 + lane * 4, &Gbuf[bufi][i_ * 2048 + w * 256]); \
    } while (0)

    if (t0 < tmax) STAGE(0, 0);
    __syncthreads();

    for (int t = t0; t < tmax; ++t) {
        int tl = t - t0;
        int buf = tl & 1;
        if (t + 1 < tmax) STAGE(buf ^ 1, tl + 1);

        // ---- phase A: MFMA gates ----
        f32x4 acc[5];
        #pragma unroll
        for (int q = 0; q < 5; ++q) acc[q] = (f32x4){0.f, 0.f, 0.f, 0.f};
        #pragma unroll
        for (int ks = 0; ks < 5; ++ks) {
            bf16x8 ah = *(const bf16x8*)&h_hi[ml][ks * 32 + fr];
            bf16x8 al = *(const bf16x8*)&h_lo[ml][ks * 32 + fr];
            #pragma unroll
            for (int q = 0; q < 5; ++q) {
                acc[q] = __builtin_amdgcn_mfma_f32_16x16x32_bf16(ah, Bh[q][ks], acc[q], 0, 0, 0);
                acc[q] = __builtin_amdgcn_mfma_f32_16x16x32_bf16(ah, Bl[q][ks], acc[q], 0, 0, 0);
                acc[q] = __builtin_amdgcn_mfma_f32_16x16x32_bf16(al, Bh[q][ks], acc[q], 0, 0, 0);
            }
        }
        // activation in C-layout: acc[q][r] = gate[batch m=quad*4+r][col ncol]
        #pragma unroll
        for (int q = 0; q < 5; ++q) {
            int ncol = w * 80 + q * 16 + ml;
            if (ncol < NG) {
                int g = ncol / HIDN, u = ncol - g * HIDN;
                bool isg = (g == 2);
                #pragma unroll
                for (int r = 0; r < 4; ++r) {
                    int m = quad * 4 + r;
                    float a = acc[q][r] + Gbuf[buf][m * NGP + ncol];
                    float bb = isg ? 2.f * a : a;
                    float e  = __expf(-bb);
                    float rr = 1.f / (1.f + e);
                    gate_s[GS(g, u, m)] = isg ? 2.f * rr - 1.f : rr;
                }
            }
        }
        __syncthreads();

        // ---- phase B: LSTM cell update, 2400 (m,u) pairs over 512 threads ----
        #pragma unroll
        for (int p = 0; p < 5; ++p) {
            int pi = tid + 512 * p;
            if (pi < 16 * HIDN) {
                int m = pi / HIDN, u = pi - m * HIDN;
                float iv = gate_s[GS(0, u, m)];
                float fv = gate_s[GS(1, u, m)];
                float gv = gate_s[GS(2, u, m)];
                float ov = gate_s[GS(3, u, m)];
                float cn = fv * creg[p] + iv * gv;
                float e2 = __expf(-2.f * cn);
                float th = 2.f / (1.f + e2) - 1.f;
                float hv = ov * th;
                int ln = len_s[m];
                bool upd = (t < ln);
                unsigned short hi = f2bf(hv);
                unsigned short lo = f2bf(hv - bf2f(hi));
                if (upd) {
                    creg[p] = cn; hreg[p] = hv;
                    h_hi[m][u] = hi; h_lo[m][u] = lo;
                }
                if (Aout) {
                    size_t off = ((size_t)(bl16 + m) * TT + t) * KPA + u;
                    Aout[off]  = upd ? hi : (unsigned short)0;
                    Alout[off] = upd ? lo : (unsigned short)0;
                }
                if (t == ln - 1) hnb[(bB + m) * HIDN + u] = hv;
            }
        }
        __syncthreads();
    }

    #pragma unroll
    for (int p = 0; p < 5; ++p) {
        int pi = tid + 512 * p;
        if (pi < 16 * HIDN) {
            int m = pi / HIDN, u = pi - m * HIDN;
            hst[(bl16 + m) * HIDN + u] = hreg[p];
            cst[(bl16 + m) * HIDN + u] = creg[p];
        }
    }
}

// ---------------- fc1+relu+fc2 head ----------------
__global__ __launch_bounds__(256) void head_kernel(
    const float* __restrict__ hnb, const float* __restrict__ fc1_w,
    const float* __restrict__ fc1_b, const float* __restrict__ fc2_w,
    const float* __restrict__ fc2_b, float* __restrict__ out)
{
    __shared__ float hs[HIDN];
    __shared__ float zs[HIDN];
    int b = blockIdx.x, tid = threadIdx.x;
    if (tid < HIDN) hs[tid] = hnb[b * HIDN + tid];
    __syncthreads();
    if (tid < HIDN) {
        float acc = fc1_b[tid];
        const float* wr = fc1_w + (size_t)tid * HIDN;
        #pragma unroll 5
        for (int k = 0; k < HIDN; ++k) acc += wr[k] * hs[k];
        zs[tid] = fmaxf(acc, 0.f);
    }
    __syncthreads();
    if (tid == 0) {
        float s = fc2_b[0];
        for (int k = 0; k < HIDN; ++k) s += fc2_w[k] * zs[k];
        out[b] = s;
    }
}

extern "C" void kernel_launch(void* const* d_in, const int* in_sizes, int n_in,
                              void* d_out, int out_size, void* d_ws, size_t ws_size,
                              hipStream_t stream)
{
    const int*   x       = (const int*)d_in[0];
    const int*   lengths = (const int*)d_in[1];
    const float* emb     = (const float*)d_in[2];
    const float *Wih[4], *Whh[4], *bih[4], *bhh[4];
    for (int l = 0; l < 4; ++l) {
        Wih[l] = (const float*)d_in[3 + 4 * l];
        Whh[l] = (const float*)d_in[4 + 4 * l];
        bih[l] = (const float*)d_in[5 + 4 * l];
        bhh[l] = (const float*)d_in[6 + 4 * l];
    }
    const float* fc1_w = (const float*)d_in[19];
    const float* fc1_b = (const float*)d_in[20];
    const float* fc2_w = (const float*)d_in[21];
    const float* fc2_b = (const float*)d_in[22];

    int Kl[4] = {300, 150, 150, 150};
    int Kp[4] = {KPE, KPA, KPA, KPA};
    size_t wioff[4], wiacc = 0;    // ushort offsets, hi block (lo follows)
    for (int l = 0; l < 4; ++l) { wioff[l] = wiacc; wiacc += 2 * (size_t)NGP * Kp[l]; }
    // wiacc = 1,024,000 ushorts

    // ---- adaptive workspace sizing ----
    size_t wf = ws_size / sizeof(float);
    const size_t WFIX = 2560 + 38400 + 512000 + 409600 + 16000000;
    int NBc = 0, Tc = 0;
    for (int nb = 256; nb >= 16; nb >>= 1) {
        for (int tc = 512; tc >= 8; tc >>= 1) {
            size_t need = WFIX + (size_t)nb * 300
                        + (size_t)nb * TT * (KPA / 2) * 2          // Ah+Al bf16
                        + (size_t)nb * tc * NGP;                   // G chunk
            if (need <= wf) { NBc = nb; Tc = tc; break; }
        }
        if (NBc) break;
    }
    if (!NBc) return;
    int lTc = __builtin_ctz(Tc);

    float* ws  = (float*)d_ws;
    float* bsm = ws;                                    // 4 * 640
    float* hnb = bsm + 2560;                            // 256*150
    unsigned short* WgI = (unsigned short*)(hnb + 38400);       // 1,024,000 ushorts (Wih splits)
    unsigned short* WgH = WgI + 1024000;                        //   819,200 ushorts (Whh splits)
    unsigned short* embh = WgH + 819200;                        // 16,000,000
    unsigned short* embl = embh + 16000000;                     // 16,000,000
    float* hst = (float*)(embl + 16000000);             // NBc*150
    float* cst = hst + (size_t)NBc * HIDN;              // NBc*150
    unsigned short* Ahh = (unsigned short*)(cst + (size_t)NBc * HIDN);  // NBc*512*160
    unsigned short* Ahl = Ahh + (size_t)NBc * TT * KPA;                 // NBc*512*160
    float* G   = (float*)(Ahl + (size_t)NBc * TT * KPA);                // NBc*Tc*640

    embprep_kernel<<<(50000 * KPE + 255) / 256, 256, 0, stream>>>(emb, embh, embl);
    for (int l = 0; l < 4; ++l) {
        split_kernel<<<(NGP * Kp[l] + 255) / 256, 256, 0, stream>>>(
            Wih[l], Kl[l], Kp[l], WgI + wioff[l], WgI + wioff[l] + (size_t)NGP * Kp[l]);
        split_kernel<<<(NGP * KPA + 255) / 256, 256, 0, stream>>>(
            Whh[l], HIDN, KPA,
            WgH + (size_t)l * 2 * NGP * KPA, WgH + (size_t)l * 2 * NGP * KPA + NGP * KPA);
        bias_kernel<<<3, 256, 0, stream>>>(bih[l], bhh[l], bsm + l * 640);
    }

    int nTc = TT / Tc;
    int nBc = NBATCH / NBc;
    dim3 ggrid((unsigned)(NBc * Tc / 128), 5);
    for (int bc = 0; bc < nBc; ++bc) {
        int b_off = bc * NBc;
        for (int l = 0; l < 4; ++l) {
            const unsigned short* WhI = WgI + wioff[l];
            const unsigned short* WlI = WhI + (size_t)NGP * Kp[l];
            const unsigned short* WhH = WgH + (size_t)l * 2 * NGP * KPA;
            const unsigned short* WlH = WhH + (size_t)NGP * KPA;
            for (int tc = 0; tc < nTc; ++tc) {
                int t0 = tc * Tc;
                gemm_kernel<<<ggrid, 256, 0, stream>>>(
                    (l == 0) ? nullptr : Ahh, (l == 0) ? nullptr : Ahl,
                    (l == 0) ? x : nullptr, embh, embl,
                    Kp[l], WhI, WlI, bsm + l * 640, lengths, G, b_off, t0, lTc);
                scan_kernel<<<NBc / 16, 512, 0, stream>>>(
                    G, WhH, WlH, lengths,
                    (l == 3) ? nullptr : Ahh, (l == 3) ? nullptr : Ahl,
                    hnb, hst, cst, b_off, t0, Tc);
            }
        }
    }
    head_kernel<<<256, 256, 0, stream>>>(hnb, fc1_w, fc1_b, fc2_w, fc2_b, (float*)d_out);
}

// Round 7
// 4923.862 us; speedup vs baseline: 2.6952x; 2.6952x over previous
//
#include <hip/hip_runtime.h>

#define HIDN 150
#define NG   600     // 4*HIDN gates
#define NGP  640     // padded gate width / G row stride / scan slot count
#define TT   512
#define NBATCH 256
#define KPA  160     // padded K for H->next-layer A buffers
#define KPE  320     // padded K for embedding
#define WROWS 152    // Whh^T rows padded (150 real + 2 zero) -> 38 float4 per thread

typedef __attribute__((ext_vector_type(8))) short bf16x8;
typedef __attribute__((ext_vector_type(4))) float f32x4;

__device__ __forceinline__ unsigned short f2bf(float v) {
    unsigned int u = __builtin_bit_cast(unsigned int, v);
    u += 0x7fffu + ((u >> 16) & 1u);          // RNE
    return (unsigned short)(u >> 16);
}
__device__ __forceinline__ float bf2f(unsigned short h) {
    unsigned int u = ((unsigned int)h) << 16;
    return __builtin_bit_cast(float, u);
}

#define GLDS(gp, lp) __builtin_amdgcn_global_load_lds( \
    (const __attribute__((address_space(1))) unsigned int*)(gp), \
    (__attribute__((address_space(3))) unsigned int*)(lp), 16, 0, 0)

// scan slot for gate column n (n<600): u=n%150, g=n/150 -> s = (u>>4)*64 + g*16 + (u&15)
__device__ __forceinline__ int slot_of(int n) {
    int g = n / HIDN, u = n - g * HIDN;
    return ((u >> 4) << 6) + (g << 4) + (u & 15);
}

// ---------------- embedding split: emb[50000][300] fp32 -> embh/embl [50000][320] bf16 ----------------
__global__ __launch_bounds__(256) void embprep_kernel(
    const float* __restrict__ emb,
    unsigned short* __restrict__ eh, unsigned short* __restrict__ el)
{
    int i = blockIdx.x * 256 + threadIdx.x;
    if (i >= 50000 * KPE) return;
    int v = i / KPE, k = i - v * KPE;
    float x = (k < 300) ? emb[(size_t)v * 300 + k] : 0.f;
    unsigned short hi = f2bf(x);
    eh[i] = hi;
    el[i] = f2bf(x - bf2f(hi));
}

// ---------------- per-layer weight prep ----------------
// Wgh/Wgl: [640][Kp] bf16 hi/lo of Wih; Wts: [152][640] fp32 Whh^T PERMUTED slot order
// (rows 150,151 zero); bsum: [640] fp32 bih+bhh (natural order, gemm epilogue).
__global__ __launch_bounds__(256) void prep_kernel(
    const float* __restrict__ Wih, const float* __restrict__ Whh,
    const float* __restrict__ bih, const float* __restrict__ bhh,
    int K, int Kp,
    unsigned short* __restrict__ Wgh, unsigned short* __restrict__ Wgl,
    float* __restrict__ Wts, float* __restrict__ bsum)
{
    int i = blockIdx.x * 256 + threadIdx.x;
    int nW = NGP * Kp;
    if (i < nW) {
        int n = i / Kp, k = i - n * Kp;
        float w = (n < NG && k < K) ? Wih[(size_t)n * K + k] : 0.f;
        unsigned short hi = f2bf(w);
        Wgh[i] = hi;
        Wgl[i] = f2bf(w - bf2f(hi));
    } else if (i < nW + WROWS * NGP) {
        int j = i - nW;
        int k = j / NGP, s = j - k * NGP;
        // invert slot: u = (s>>6)*16 + (s&15), g = (s>>4)&3
        int u = ((s >> 6) << 4) + (s & 15);
        int g = (s >> 4) & 3;
        Wts[j] = (u < HIDN && k < HIDN) ? Whh[(size_t)(g * HIDN + u) * HIDN + k] : 0.f;
    } else if (i < nW + WROWS * NGP + NGP) {
        int g = i - nW - WROWS * NGP;
        bsum[g] = (g < NG) ? (bih[g] + bhh[g]) : 0.f;
    }
}

// ---------------- x_proj GEMM: split-bf16 MFMA ----------------
// G written in PERMUTED slot order, row stride 640 (scan reads G[row][tid] coalesced).
__global__ __launch_bounds__(256, 2) void gemm_kernel(
    const unsigned short* __restrict__ Ah, const unsigned short* __restrict__ Al,
    const int* __restrict__ gather,
    const unsigned short* __restrict__ Eh, const unsigned short* __restrict__ El,
    int Kp,
    const unsigned short* __restrict__ Wh, const unsigned short* __restrict__ Wl,
    const float* __restrict__ bsum, const int* __restrict__ lengths,
    float* __restrict__ G,                                       // [NBc*Tc][640] permuted
    int b_off, int t0, int lTc)
{
    int m0 = blockIdx.x * 128;
    int n0 = blockIdx.y * 128;
    int Tcm1 = (1 << lTc) - 1;
    if (lTc >= 7) {
        int b = b_off + (m0 >> lTc);
        if (t0 + (m0 & Tcm1) >= lengths[b]) return;
    }

    __shared__ __align__(16) unsigned short Ash[128][32];
    __shared__ __align__(16) unsigned short Asl[128][32];
    __shared__ __align__(16) unsigned short Bsh[128][32];
    __shared__ __align__(16) unsigned short Bsl[128][32];

    int tid = threadIdx.x, lane = tid & 63, wave = tid >> 6;

    const unsigned short* AhB = gather ? Eh : Ah;
    const unsigned short* AlB = gather ? El : Al;
    size_t ra[2], rb[2];
    int mrow[2];
    #pragma unroll
    for (int c2 = 0; c2 < 2; ++c2) {
        int mb = wave * 32 + c2 * 16;
        mrow[c2] = mb;
        int rg = m0 + mb + (lane >> 2);
        int bb = rg >> lTc, tl = rg & Tcm1;
        ra[c2] = gather ? (size_t)gather[(b_off + bb) * TT + t0 + tl] * (size_t)Kp
                        : ((size_t)bb * TT + t0 + tl) * (size_t)Kp;
        int nr = n0 + mb + (lane >> 2);
        rb[c2] = (size_t)nr * (size_t)Kp;
    }
    int klane = (lane & 3) * 8;

    f32x4 acc[4][4];
    #pragma unroll
    for (int i = 0; i < 4; ++i)
        #pragma unroll
        for (int j = 0; j < 4; ++j) acc[i][j] = (f32x4){0.f, 0.f, 0.f, 0.f};

    int fr = (lane >> 4) * 8;
    int ml = lane & 15;
    int mbase = (wave & 1) * 64;
    int nbase = (wave >> 1) * 64;

    for (int k0 = 0; k0 < Kp; k0 += 32) {
        #pragma unroll
        for (int c2 = 0; c2 < 2; ++c2) {
            GLDS(AhB + ra[c2] + k0 + klane, &Ash[mrow[c2]][0]);
            GLDS(AlB + ra[c2] + k0 + klane, &Asl[mrow[c2]][0]);
            GLDS(Wh  + rb[c2] + k0 + klane, &Bsh[mrow[c2]][0]);
            GLDS(Wl  + rb[c2] + k0 + klane, &Bsl[mrow[c2]][0]);
        }
        __syncthreads();

        bf16x8 afh[4], afl[4], bfh[4], bfl[4];
        #pragma unroll
        for (int i = 0; i < 4; ++i) {
            afh[i] = *(const bf16x8*)&Ash[mbase + i * 16 + ml][fr];
            afl[i] = *(const bf16x8*)&Asl[mbase + i * 16 + ml][fr];
            bfh[i] = *(const bf16x8*)&Bsh[nbase + i * 16 + ml][fr];
            bfl[i] = *(const bf16x8*)&Bsl[nbase + i * 16 + ml][fr];
        }
        #pragma unroll
        for (int i = 0; i < 4; ++i)
            #pragma unroll
            for (int j = 0; j < 4; ++j)
                acc[i][j] = __builtin_amdgcn_mfma_f32_16x16x32_bf16(afh[i], bfh[j], acc[i][j], 0, 0, 0);
        #pragma unroll
        for (int i = 0; i < 4; ++i)
            #pragma unroll
            for (int j = 0; j < 4; ++j)
                acc[i][j] = __builtin_amdgcn_mfma_f32_16x16x32_bf16(afh[i], bfl[j], acc[i][j], 0, 0, 0);
        #pragma unroll
        for (int i = 0; i < 4; ++i)
            #pragma unroll
            for (int j = 0; j < 4; ++j)
                acc[i][j] = __builtin_amdgcn_mfma_f32_16x16x32_bf16(afl[i], bfh[j], acc[i][j], 0, 0, 0);
        __syncthreads();
    }

    // epilogue: C/D layout col=lane&15, row=(lane>>4)*4+r; store into permuted slot
    int rq = lane >> 4;
    #pragma unroll
    for (int i = 0; i < 4; ++i) {
        int mg = m0 + mbase + i * 16 + rq * 4;
        #pragma unroll
        for (int j = 0; j < 4; ++j) {
            int ng = n0 + nbase + j * 16 + ml;
            if (ng < NG) {
                float bz = bsum[ng];
                int s = slot_of(ng);
                #pragma unroll
                for (int r = 0; r < 4; ++r)
                    G[(size_t)(mg + r) * NGP + s] = acc[i][j][r] + bz;
            }
        }
    }
}

// ---------------- recurrent scan: permuted slots, all weights in VGPRs ----------------
// 640 threads = 10 waves. Wave w lane l owns gate column g*150+u, u=w*16+(l&15), g=l>>4.
// Whh^T (permuted, 152 rows) fully register-resident: 38 float4 = 152 VGPRs.
// __launch_bounds__(640,2): 256-reg cap so weights stay in arch VGPRs (no accvgpr moves).
#define REGK 38

__global__ __launch_bounds__(640, 2) void scan_kernel(
    const float* __restrict__ G,       // [NBc][Tc][640] permuted x_proj+bias
    const float* __restrict__ Wt,      // [152][640] permuted Whh^T
    const int*   __restrict__ lengths,
    unsigned short* __restrict__ Aout, // [NBc][512][160] bf16-hi h, or null (layer 3)
    unsigned short* __restrict__ Alout,
    float* __restrict__ hnb,           // [256][150]
    float* __restrict__ hst, float* __restrict__ cst,   // [NBc][150] carries
    int b_off, int t0, int Tc)
{
    __shared__ __align__(16) float h_s[2][160];

    int tid = threadIdx.x;
    int lane = tid & 63, w = tid >> 6;
    int u_loc = lane & 15, g = (lane >> 4) & 3;
    int u = w * 16 + u_loc;
    bool own = (lane < 16) && (u < HIDN);

    int l0 = blockIdx.x;
    int b  = b_off + l0;
    int len = lengths[b];
    int tmax = min(len, t0 + Tc);

    float4 wr[REGK];
    #pragma unroll
    for (int q = 0; q < REGK; ++q) {
        wr[q].x = Wt[(4 * q + 0) * NGP + tid];
        wr[q].y = Wt[(4 * q + 1) * NGP + tid];
        wr[q].z = Wt[(4 * q + 2) * NGP + tid];
        wr[q].w = Wt[(4 * q + 3) * NGP + tid];
    }

    float c = 0.f;
    if (tid < 160) { h_s[0][tid] = 0.f; h_s[1][tid] = 0.f; }
    if (tid < HIDN && t0 > 0) h_s[0][tid] = hst[l0 * HIDN + tid];
    if (own && t0 > 0) c = cst[l0 * HIDN + u];

    bool isg = (g == 2);                      // g-gate -> tanh
    const float* Gbase = G + (size_t)l0 * Tc * NGP + tid;
    __syncthreads();

    int p = 0;
    float gnext = (t0 < tmax) ? Gbase[(size_t)0] : 0.f;
    for (int t = t0; t < tmax; ++t) {
        float gcur = gnext;
        if (t + 1 < tmax) gnext = Gbase[(size_t)(t + 1 - t0) * NGP];   // prefetch next step
        const float* hp = &h_s[p][0];
        float acc = 0.f;
        #pragma unroll
        for (int q = 0; q < REGK; ++q) {
            float4 h4 = *(const float4*)&hp[4 * q];                    // LDS broadcast
            acc += wr[q].x * h4.x; acc += wr[q].y * h4.y;
            acc += wr[q].z * h4.z; acc += wr[q].w * h4.w;
        }
        float a = gcur + acc;
        // per-lane activation: sigmoid (i,f,o) or tanh (g) = 2*sigmoid(2a)-1
        float bb = isg ? 2.f * a : a;
        float e  = __expf(-bb);
        float r  = 1.f / (1.f + e);
        float av = isg ? 2.f * r - 1.f : r;
        // wave-local gate gather (columns u, u+150, u+300, u+450 live in this wave)
        float fv = __shfl(av, u_loc + 16, 64);
        float gv = __shfl(av, u_loc + 32, 64);
        float ov = __shfl(av, u_loc + 48, 64);
        if (own) {
            float cn = fv * c + av * gv;       // av = i-gate on owner lanes (g==0)
            float e2 = __expf(-2.f * cn);
            float th = 2.f / (1.f + e2) - 1.f;
            float hv = ov * th;
            c = cn;
            h_s[p ^ 1][u] = hv;
            if (Aout) {
                size_t off = ((size_t)l0 * TT + t) * KPA + u;
                unsigned short hi = f2bf(hv);
                Aout[off]  = hi;
                Alout[off] = f2bf(hv - bf2f(hi));
            }
            if (t == len - 1) hnb[b * HIDN + u] = hv;
        }
        __syncthreads();
        p ^= 1;
    }

    if (own) {
        hst[l0 * HIDN + u] = h_s[p][u];
        cst[l0 * HIDN + u] = c;
    }
}

// ---------------- fc1+relu+fc2 head ----------------
__global__ __launch_bounds__(256) void head_kernel(
    const float* __restrict__ hnb, const float* __restrict__ fc1_w,
    const float* __restrict__ fc1_b, const float* __restrict__ fc2_w,
    const float* __restrict__ fc2_b, float* __restrict__ out)
{
    __shared__ float hs[HIDN];
    __shared__ float zs[HIDN];
    int b = blockIdx.x, tid = threadIdx.x;
    if (tid < HIDN) hs[tid] = hnb[b * HIDN + tid];
    __syncthreads();
    if (tid < HIDN) {
        float acc = fc1_b[tid];
        const float* wr = fc1_w + (size_t)tid * HIDN;
        #pragma unroll 5
        for (int k = 0; k < HIDN; ++k) acc += wr[k] * hs[k];
        zs[tid] = fmaxf(acc, 0.f);
    }
    __syncthreads();
    if (tid == 0) {
        float s = fc2_b[0];
        for (int k = 0; k < HIDN; ++k) s += fc2_w[k] * zs[k];
        out[b] = s;
    }
}

extern "C" void kernel_launch(void* const* d_in, const int* in_sizes, int n_in,
                              void* d_out, int out_size, void* d_ws, size_t ws_size,
                              hipStream_t stream)
{
    const int*   x       = (const int*)d_in[0];
    const int*   lengths = (const int*)d_in[1];
    const float* emb     = (const float*)d_in[2];
    const float *Wih[4], *Whh[4], *bih[4], *bhh[4];
    for (int l = 0; l < 4; ++l) {
        Wih[l] = (const float*)d_in[3 + 4 * l];
        Whh[l] = (const float*)d_in[4 + 4 * l];
        bih[l] = (const float*)d_in[5 + 4 * l];
        bhh[l] = (const float*)d_in[6 + 4 * l];
    }
    const float* fc1_w = (const float*)d_in[19];
    const float* fc1_b = (const float*)d_in[20];
    const float* fc2_w = (const float*)d_in[21];
    const float* fc2_b = (const float*)d_in[22];

    int Kl[4]  = {300, 150, 150, 150};
    int Kp[4]  = {KPE, KPA, KPA, KPA};
    size_t wgoff[4];
    size_t wgacc = 0;
    for (int l = 0; l < 4; ++l) { wgoff[l] = wgacc; wgacc += 2 * (size_t)NGP * Kp[l]; }
    const int WTS_STRIDE = WROWS * NGP;              // 97280 floats per layer

    // ---- adaptive workspace sizing ----
    size_t wf = ws_size / sizeof(float);
    const size_t WFIX = (size_t)4 * WTS_STRIDE + 2560 + 38400 + 512000 + 16000000;
    int NBc = 0, Tc = 0;
    for (int nb = 256; nb >= 16; nb >>= 1) {
        for (int tc = 512; tc >= 8; tc >>= 1) {
            size_t need = WFIX + (size_t)nb * 300
                        + (size_t)nb * TT * KPA                   // Ah+Al (2 bufs of bf16)
                        + (size_t)nb * tc * NGP;                  // G chunk (stride 640)
            if (need <= wf) { NBc = nb; Tc = tc; break; }
        }
        if (NBc) break;
    }
    if (!NBc) return;
    int lTc = __builtin_ctz(Tc);

    float* ws  = (float*)d_ws;
    float* Wts = ws;                                    // 4 * 97280 (permuted, 152 rows)
    float* bsm = Wts + 4 * WTS_STRIDE;                  // 4 * 640
    float* hnb = bsm + 2560;                            // 256*150
    unsigned short* Wg = (unsigned short*)(hnb + 38400);        // 1,024,000 ushorts
    unsigned short* embh = Wg + 1024000;                        // 16,000,000 ushorts
    unsigned short* embl = embh + 16000000;                     // 16,000,000 ushorts
    float* hst = (float*)(embl + 16000000);             // NBc*150
    float* cst = hst + (size_t)NBc * HIDN;              // NBc*150
    unsigned short* Ahh = (unsigned short*)(cst + (size_t)NBc * HIDN);  // NBc*512*160
    unsigned short* Ahl = Ahh + (size_t)NBc * TT * KPA;                 // NBc*512*160
    float* G   = (float*)(Ahl + (size_t)NBc * TT * KPA);                // NBc*Tc*640

    embprep_kernel<<<(50000 * KPE + 255) / 256, 256, 0, stream>>>(emb, embh, embl);
    for (int l = 0; l < 4; ++l) {
        int total = NGP * Kp[l] + WROWS * NGP + NGP;
        prep_kernel<<<(total + 255) / 256, 256, 0, stream>>>(
            Wih[l], Whh[l], bih[l], bhh[l], Kl[l], Kp[l],
            Wg + wgoff[l], Wg + wgoff[l] + (size_t)NGP * Kp[l],
            Wts + l * WTS_STRIDE, bsm + l * 640);
    }

    int nTc = TT / Tc;
    int nBc = NBATCH / NBc;
    dim3 ggrid((unsigned)(NBc * Tc / 128), 5);
    for (int bc = 0; bc < nBc; ++bc) {
        int b_off = bc * NBc;
        for (int l = 0; l < 4; ++l) {
            const unsigned short* Wh = Wg + wgoff[l];
            const unsigned short* Wl = Wh + (size_t)NGP * Kp[l];
            for (int tc = 0; tc < nTc; ++tc) {
                int t0 = tc * Tc;
                gemm_kernel<<<ggrid, 256, 0, stream>>>(
                    (l == 0) ? nullptr : Ahh, (l == 0) ? nullptr : Ahl,
                    (l == 0) ? x : nullptr, embh, embl,
                    Kp[l], Wh, Wl, bsm + l * 640, lengths, G, b_off, t0, lTc);
                scan_kernel<<<NBc, 640, 0, stream>>>(
                    G, Wts + l * WTS_STRIDE, lengths,
                    (l == 3) ? nullptr : Ahh, (l == 3) ? nullptr : Ahl,
                    hnb, hst, cst, b_off, t0, Tc);
            }
        }
    }
    head_kernel<<<256, 256, 0, stream>>>(hnb, fc1_w, fc1_b, fc2_w, fc2_b, (float*)d_out);
}